// Round 8
// baseline (681.814 us; speedup 1.0000x reference)
//
#include <hip/hip_runtime.h>

#define K_NEIGH 32
#define D_FEAT  128

__device__ __forceinline__ float readlane_f(float v, int l) {
    return __int_as_float(__builtin_amdgcn_readlane(__float_as_int(v), l));
}

// ---- R3 math, split into pipeline-able phases ----

__device__ __forceinline__ void load_elem(const float* __restrict__ features,
                                          const int* __restrict__ nodes,
                                          const int* __restrict__ neighs,
                                          int b, int lane,
                                          float2& c, float2 v[K_NEIGH],
                                          const int*& nb) {
    nb = neighs + (size_t)b * K_NEIGH;
    const int cnode = nodes[b];
    c = ((const float2*)(features + (size_t)cnode * D_FEAT))[lane];
    #pragma unroll
    for (int r = 0; r < K_NEIGH; ++r) {
        const int nidx = nb[r];              // wave-uniform -> s_load
        v[r] = ((const float2*)(features + (size_t)nidx * D_FEAT))[lane];
    }
}

__device__ __forceinline__ void consume(const float2& c, const float2 v[K_NEIGH],
                                        int lane, float* dt, float* n2, float& cn) {
    float cc = c.x * c.x + c.y * c.y;
    #pragma unroll
    for (int m = 32; m >= 1; m >>= 1) cc += __shfl_xor(cc, m);
    cn = sqrtf(cc);
    #pragma unroll
    for (int r = 0; r < K_NEIGH; ++r) {
        dt[r] = c.x * v[r].x + c.y * v[r].y;
        n2[r] = v[r].x * v[r].x + v[r].y * v[r].y;
    }
}

__device__ __forceinline__ unsigned foldrank(float* dt, float* n2, float cn,
                                             int lane, int ns) {
    #pragma unroll
    for (int o = 32; o >= 2; o >>= 1) {
        const bool up = (lane & o) != 0;
        #pragma unroll
        for (int r = 0; r < o / 2; ++r) {
            const float sd = up ? dt[r] : dt[r + o / 2];
            const float sn = up ? n2[r] : n2[r + o / 2];
            const float rd = __shfl_xor(sd, o);
            const float rn = __shfl_xor(sn, o);
            const float kd = up ? dt[r + o / 2] : dt[r];
            const float kn = up ? n2[r + o / 2] : n2[r];
            dt[r] = kd + rd;
            n2[r] = kn + rn;
        }
    }
    dt[0] += __shfl_xor(dt[0], 1);
    n2[0] += __shfl_xor(n2[0], 1);

    const int   myrow = lane >> 1;
    const float sim   = dt[0] / (cn * sqrtf(n2[0]));

    int rank = 0;
    #pragma unroll
    for (int j = 0; j < K_NEIGH; ++j) {
        const float sj = readlane_f(sim, 2 * j);
        rank += (sj > sim || (sj == sim && j < myrow)) ? 1 : 0;
    }
    const unsigned long long bal = __ballot(rank < ns);
    unsigned long long x = bal & 0x5555555555555555ull;
    x = (x | (x >> 1))  & 0x3333333333333333ull;
    x = (x | (x >> 2))  & 0x0F0F0F0F0F0F0F0Full;
    x = (x | (x >> 4))  & 0x00FF00FF00FF00FFull;
    x = (x | (x >> 8))  & 0x0000FFFF0000FFFFull;
    x = (x | (x >> 16)) & 0x00000000FFFFFFFFull;
    return __builtin_amdgcn_readfirstlane((unsigned)x);
}

__device__ __forceinline__ void mean_store(const float* __restrict__ features,
                                           const int* __restrict__ nb,
                                           unsigned mask, int lane, int ns,
                                           float* __restrict__ out, int b) {
    // Explicit re-gather of all 32 rows (independent, L1/L2-hot) +
    // predicated FMA — the pattern that made R3 fast, now intentional.
    float2 acc = make_float2(0.f, 0.f);
    #pragma unroll
    for (int j = 0; j < K_NEIGH; ++j) {
        const int    nidx = nb[j];
        const float2 v = ((const float2*)(features + (size_t)nidx * D_FEAT))[lane];
        const float  w = (float)((mask >> j) & 1u);
        acc.x = fmaf(v.x, w, acc.x);
        acc.y = fmaf(v.y, w, acc.y);
    }
    const float nsf = (float)ns;
    float2 ov;
    ov.x = fmaxf(acc.x / nsf, 0.f);
    ov.y = fmaxf(acc.y / nsf, 0.f);
    ((float2*)(out + (size_t)b * D_FEAT))[lane] = ov;
}

// Each wave processes TWO batch elements, software-pipelined: element e1's
// 33 loads are issued between e0's consume and e0's fold/rank/mean (~1000
// cycles of overlap), so e1's latency is hidden intra-wave instead of
// relying solely on cross-wave TLP.
__global__ __launch_bounds__(256, 3) void intra_agg_kernel(
    const float* __restrict__ features,
    const int*   __restrict__ nodes,
    const int*   __restrict__ neighs,
    const int*   __restrict__ num_sample_p,
    float*       __restrict__ out,
    int batch)
{
    const int tid  = blockIdx.x * blockDim.x + threadIdx.x;
    const int lane = threadIdx.x & 63;
    int wid = tid >> 6;
    const int b0 = __builtin_amdgcn_readfirstlane(2 * wid);
    if (b0 >= batch) return;
    const int b1 = b0 + 1;
    const int ns = *num_sample_p;

    float dt[K_NEIGH], n2[K_NEIGH];
    float cn;

    // --- element 0: load + consume ---
    float2 c0, v0[K_NEIGH];
    const int* nb0;
    load_elem(features, nodes, neighs, b0, lane, c0, v0, nb0);
    consume(c0, v0, lane, dt, n2, cn);          // waits on v0 here

    // --- element 1: issue loads now (overlap with e0's fold/rank/mean) ---
    float2 c1, v1[K_NEIGH];
    const int* nb1 = nullptr;
    const bool have1 = (b1 < batch);            // uniform (batch even)
    if (have1) load_elem(features, nodes, neighs, b1, lane, c1, v1, nb1);
    __builtin_amdgcn_sched_barrier(0);          // don't sink those loads

    // --- element 0: reduce, rank, mean, store ---
    const unsigned mask0 = foldrank(dt, n2, cn, lane, ns);
    mean_store(features, nb0, mask0, lane, ns, out, b0);

    // --- element 1: consume (loads long since landed), reduce, mean, store ---
    if (have1) {
        consume(c1, v1, lane, dt, n2, cn);
        const unsigned mask1 = foldrank(dt, n2, cn, lane, ns);
        mean_store(features, nb1, mask1, lane, ns, out, b1);
    }
}

extern "C" void kernel_launch(void* const* d_in, const int* in_sizes, int n_in,
                              void* d_out, int out_size, void* d_ws, size_t ws_size,
                              hipStream_t stream) {
    const float* features = (const float*)d_in[0];
    const int*   nodes    = (const int*)d_in[1];
    const int*   neighs   = (const int*)d_in[2];
    const int*   ns       = (const int*)d_in[3];
    float*       out      = (float*)d_out;

    const int batch = in_sizes[1];                   // 32768
    const int waves = (batch + 1) / 2;               // 2 elements per wave
    const int blocks = (waves + 3) / 4;              // 4 waves per 256-thr block

    intra_agg_kernel<<<blocks, 256, 0, stream>>>(features, nodes, neighs, ns, out, batch);
}